// Round 1
// baseline (214.212 us; speedup 1.0000x reference)
//
#include <hip/hip_runtime.h>
#include <math.h>

// Cells per anchor-plane (S*S = 52*52)
#define CPG (52 * 52)

__device__ __forceinline__ float softplusf(float x) {
    // stable softplus: log(1+e^x)
    if (x > 20.f)  return x;
    if (x < -20.f) return expf(x);
    return log1pf(expf(x));
}

__device__ __forceinline__ float sigmoidf(float x) {
    return 1.f / (1.f + expf(-x));
}

// acc layout: [0]=box_sum [1]=obj_sum [2]=noobj_sum [3]=cls_sum [4]=n_obj [5]=n_noobj
__global__ __launch_bounds__(256) void yolo_partial_kernel(
    const float* __restrict__ pred,   // [N_cells, 85]
    const float* __restrict__ targ,   // [N_cells, 6]
    const float* __restrict__ anchor, // [3, 2]
    float* __restrict__ acc,
    int n_cells)
{
    int idx = blockIdx.x * blockDim.x + threadIdx.x;

    float box_s = 0.f, obj_s = 0.f, noobj_s = 0.f, cls_s = 0.f;
    float nobj = 0.f, nnoobj = 0.f;

    if (idx < n_cells) {
        const float* t = targ + (size_t)idx * 6;
        const float* p = pred + (size_t)idx * 85;
        float t0 = t[0];
        float x0 = p[0];

        if (t0 == 0.0f) {
            // no-object: BCEWithLogits(x0, 0) = softplus(x0)
            noobj_s = softplusf(x0);
            nnoobj  = 1.f;
        } else if (t0 == 1.0f) {
            nobj = 1.f;
            int a = (idx / CPG) % 3;
            float aw = anchor[a * 2 + 0];
            float ah = anchor[a * 2 + 1];

            float px = sigmoidf(p[1]);
            float py = sigmoidf(p[2]);
            float rw = p[3], rh = p[4];
            float pw = expf(rw) * aw;
            float ph = expf(rh) * ah;

            float tx = t[1], ty = t[2], tw = t[3], th = t[4];

            // IoU (midpoint format)
            float ax1 = px - pw * 0.5f, ay1 = py - ph * 0.5f;
            float ax2 = px + pw * 0.5f, ay2 = py + ph * 0.5f;
            float bx1 = tx - tw * 0.5f, by1 = ty - th * 0.5f;
            float bx2 = tx + tw * 0.5f, by2 = ty + th * 0.5f;
            float iw = fmaxf(fminf(ax2, bx2) - fmaxf(ax1, bx1), 0.f);
            float ih = fmaxf(fminf(ay2, by2) - fmaxf(ay1, by1), 0.f);
            float inter  = iw * ih;
            float area_a = fabsf((ax2 - ax1) * (ay2 - ay1));
            float area_b = fabsf((bx2 - bx1) * (by2 - by1));
            float iou = inter / (area_a + area_b - inter + 1e-6f);

            // object loss: BCEWithLogits(sigmoid(x0), iou)  [faithful double-squash]
            float sp = sigmoidf(x0);
            obj_s = softplusf(sp) - iou * sp;

            // box MSE: [sigmoid(xy), raw wh] vs [target xy, log(wh/anchor)]
            float twx = logf(1e-16f + tw / aw);
            float twy = logf(1e-16f + th / ah);
            float d1 = px - tx, d2 = py - ty, d3 = rw - twx, d4 = rh - twy;
            box_s = d1 * d1 + d2 * d2 + d3 * d3 + d4 * d4;

            // class cross-entropy: logsumexp(p[5:85]) - p[5+cls]  (online 1-pass)
            int ci = (int)t[5];
            float m = -INFINITY, se = 0.f;
            for (int c = 0; c < 80; ++c) {
                float v  = p[5 + c];
                float nm = fmaxf(m, v);
                se = se * expf(m - nm) + expf(v - nm);
                m  = nm;
            }
            cls_s = logf(se) + m - p[5 + ci];
        }
    }

    // ---- reduction: wave shuffle -> LDS cross-wave -> atomicAdd ----
    float vals[6] = {box_s, obj_s, noobj_s, cls_s, nobj, nnoobj};

    #pragma unroll
    for (int k = 0; k < 6; ++k) {
        float v = vals[k];
        #pragma unroll
        for (int off = 32; off > 0; off >>= 1)
            v += __shfl_down(v, off, 64);
        vals[k] = v;  // valid in lane 0 of each wave
    }

    __shared__ float red[6][4];
    int lane = threadIdx.x & 63;
    int wave = threadIdx.x >> 6;
    if (lane == 0) {
        #pragma unroll
        for (int k = 0; k < 6; ++k) red[k][wave] = vals[k];
    }
    __syncthreads();

    if (threadIdx.x == 0) {
        #pragma unroll
        for (int k = 0; k < 6; ++k) {
            float s = red[k][0] + red[k][1] + red[k][2] + red[k][3];
            atomicAdd(&acc[k], s);
        }
    }
}

__global__ void yolo_finalize_kernel(const float* __restrict__ acc,
                                     float* __restrict__ out)
{
    float box   = acc[0];
    float obj   = acc[1];
    float noobj = acc[2];
    float cls   = acc[3];
    float n_obj   = fmaxf(acc[4], 1.f);
    float n_noobj = fmaxf(acc[5], 1.f);

    // L_BOX*box/(4*n_obj) + L_OBJ*obj/n_obj + L_NOOBJ*noobj/n_noobj + L_CLASS*cls/n_obj
    out[0] = 10.f * box / (4.f * n_obj)
           + 5.f  * obj / n_obj
           + 1.f  * noobj / n_noobj
           + 2.f  * cls / n_obj;
}

extern "C" void kernel_launch(void* const* d_in, const int* in_sizes, int n_in,
                              void* d_out, int out_size, void* d_ws, size_t ws_size,
                              hipStream_t stream) {
    const float* pred   = (const float*)d_in[0];
    const float* targ   = (const float*)d_in[1];
    const float* anchor = (const float*)d_in[2];
    float* acc = (float*)d_ws;
    float* out = (float*)d_out;

    int n_cells = in_sizes[1] / 6;  // targets: [B,A,S,S,6]

    // d_ws is re-poisoned to 0xAA before every launch — zero the accumulators.
    hipMemsetAsync(acc, 0, 6 * sizeof(float), stream);

    int threads = 256;
    int blocks  = (n_cells + threads - 1) / threads;
    yolo_partial_kernel<<<blocks, threads, 0, stream>>>(pred, targ, anchor, acc, n_cells);
    yolo_finalize_kernel<<<1, 1, 0, stream>>>(acc, out);
}